// Round 12
// baseline (189.907 us; speedup 1.0000x reference)
//
#include <hip/hip_runtime.h>

#define TT 512
#define BB 1024
#define FF 16
#define HH 32
#define OO 8
#define CH 16             // timesteps per x-chunk
#define NC (TT / CH)      // 32 chunks
#define NG 128            // gate rows (4*HH)

typedef _Float16 f16;
typedef f16 v2h __attribute__((ext_vector_type(2)));
typedef f16 v4h __attribute__((ext_vector_type(4)));
typedef f16 v8h __attribute__((ext_vector_type(8)));
typedef float f32x4 __attribute__((ext_vector_type(4)));
typedef int   v2i  __attribute__((ext_vector_type(2)));

__device__ __forceinline__ float rcp_fast(float x) { return __builtin_amdgcn_rcpf(x); }
// inputs PRE-SCALED by log2e (resp. 2*log2e) -> plain exp2
__device__ __forceinline__ float sigm2(float y) {
    return rcp_fast(1.0f + __builtin_amdgcn_exp2f(-y));
}
__device__ __forceinline__ float fdot2(v2h a, v2h b, float c) {
    return __builtin_amdgcn_fdot2(a, b, c, false);
}
__device__ __forceinline__ v2h i2h(int s) { return __builtin_bit_cast(v2h, s); }

// cross-half exchange WITHOUT a DS op (gfx950 VALU permlane).
__device__ __forceinline__ float xhalf_swap(float v) {
#if __has_builtin(__builtin_amdgcn_permlane32_swap)
    int pi = __float_as_int(v);
    v2i sw = __builtin_amdgcn_permlane32_swap(pi, pi, false, false);
    return __int_as_float(sw.x);
#else
    return __shfl_xor(v, 32);
#endif
}

// one LSTM timestep for sequence S (A or B). tt compile-time constant.
#define LSTEP(tt, S)                                                           \
  {                                                                            \
    const int xm = ((tt) & 7) << 2;                                            \
    const float gx0 = gxc##S[(tt) * NG + (r0 ^ xm)];                           \
    const float gx1 = gxc##S[(tt) * NG + (r1 ^ xm)];                           \
    float B0 = fdot2(i2h(hs##S[0]), w0h[0], pb0);                              \
    float B1 = fdot2(i2h(hs##S[0]), w1h[0], pb1);                              \
    float C0 = fdot2(i2h(hs##S[8]), w0h[8], gx0);                              \
    float C1 = fdot2(i2h(hs##S[8]), w1h[8], gx1);                              \
    _Pragma("unroll")                                                          \
    for (int j = 1; j < 8; ++j) {                                              \
      B0 = fdot2(i2h(hs##S[j]),     w0h[j],     B0);                           \
      B1 = fdot2(i2h(hs##S[j]),     w1h[j],     B1);                           \
      C0 = fdot2(i2h(hs##S[8 + j]), w0h[8 + j], C0);                           \
      C1 = fdot2(i2h(hs##S[8 + j]), w1h[8 + j], C1);                           \
    }                                                                          \
    const float g0 = B0 + C0;                                                  \
    const float g1 = B1 + C1;                                                  \
    const float s0 = sigm2(g0);                /* si (lo) / sf (hi) */         \
    const float s1 = fmaf(sigm2(g1), pm, pa);  /* tg (lo) / so (hi) */         \
    const float prod = s0 * s1;                                                \
    const float recv = xhalf_swap(prod);                                       \
    c##S = fmaf(s0, c##S, recv);               /* hi: sf*c + si*tg */          \
    const float th = fmaf(2.0f, sigm2(L2E2 * c##S), -1.0f);                    \
    h##S = s1 * th;                            /* hi: so*tanh(c) */            \
    const int hn = __builtin_amdgcn_mov_dpp(__float_as_int(h##S),              \
                                            0xB1, 0xF, 0xF, true);             \
    auto pk = __builtin_amdgcn_cvt_pkrtz(h##S, __int_as_float(hn));            \
    const int pki = __builtin_bit_cast(int, pk);                               \
    _Pragma("unroll")                                                          \
    for (int m = 0; m < HH / 2; ++m)                                           \
      hs##S[m] = __builtin_amdgcn_readlane(pki, 32 + 2 * m);                   \
  }

// One wave per block, TWO same-direction sequences per wave (1024 blocks,
// 1 wave/SIMD, 4 blocks/CU). The two sequences share ALL weight registers
// (weights depend only on dir); their step chains are independent, so the
// in-wave interleave (A-step then B-step) fills each chain's latency gaps
// with the other's issue — wall/step drops from chain-bound (~870cy) to
// issue-bound (~350cy/seq). Everything else = r9/r11 validated structure:
// row-split full-k dots vs SGPR h; x-part batched per 16-step chunk on the
// matrix pipe into XOR-swizzled LDS; no barriers (single-wave block).
__global__ __launch_bounds__(64, 1)
void lstm_seq_kernel(const float* __restrict__ x,
                     const float* __restrict__ Wih_f, const float* __restrict__ Whh_f,
                     const float* __restrict__ b_f,
                     const float* __restrict__ Wih_b, const float* __restrict__ Whh_b,
                     const float* __restrict__ b_b,
                     float* __restrict__ hidden)
{
    const int bid  = blockIdx.x;          // 0..1023
    const int dir  = bid >> 9;            // 0 = fwd, 1 = bwd
    const int bbA  = (bid & 511) * 2;     // batch rows (same dir pair)
    const int bbB  = bbA + 1;
    const int lane = threadIdx.x;
    const int hi   = lane >> 5;           // 0: rows {i,g}   1: rows {f,o}
    const int kk   = lane & 31;

    const float* __restrict__ Wih  = dir ? Wih_b : Wih_f;
    const float* __restrict__ Whh  = dir ? Whh_b : Whh_f;
    const float* __restrict__ bias = dir ? b_b   : b_f;

    const float LOG2E = 1.4426950408889634f;
    const float L2E2  = 2.0f * LOG2E;

    const int r0 = kk + hi * HH;      // i (hi=0) / f (hi=1)
    const int r1 = r0 + 2 * HH;       // g (hi=0) / o (hi=1)
    const float sc0 = LOG2E;
    const float sc1 = hi ? LOG2E : L2E2;
    const float pm = hi ? 1.0f : 2.0f;
    const float pa = hi ? 0.0f : -1.0f;

    // ---- recurrent weights (shared by both seqs): f16 pairs, pre-scaled ----
    v2h w0h[HH / 2], w1h[HH / 2];
#pragma unroll
    for (int q = 0; q < HH / 4; ++q) {
        float4 a = ((const float4*)(Whh + r0 * HH))[q];
        w0h[2*q]   = (v2h){(f16)(a.x * sc0), (f16)(a.y * sc0)};
        w0h[2*q+1] = (v2h){(f16)(a.z * sc0), (f16)(a.w * sc0)};
        float4 b2 = ((const float4*)(Whh + r1 * HH))[q];
        w1h[2*q]   = (v2h){(f16)(b2.x * sc1), (f16)(b2.y * sc1)};
        w1h[2*q+1] = (v2h){(f16)(b2.z * sc1), (f16)(b2.w * sc1)};
    }
    const float pb0 = bias[r0] * sc0;
    const float pb1 = bias[r1] * sc1;

    // ---- MFMA A-fragments for the x-GEMM (shared), k padded 16->32 ----
    v8h awx[8];
#pragma unroll
    for (int T = 0; T < 8; ++T) {
        v8h t = {(f16)0,(f16)0,(f16)0,(f16)0,(f16)0,(f16)0,(f16)0,(f16)0};
        if (lane < 32) {
            const int gate = T * 16 + (lane & 15);
            const float sc = (gate >= 64 && gate < 96) ? L2E2 : LOG2E;
            const float* wrow = Wih + gate * FF + (lane >> 4) * 8;
#pragma unroll
            for (int j = 0; j < 8; ++j) t[j] = (f16)(wrow[j] * sc);
        }
        awx[T] = t;
    }

    __shared__ __align__(16) f16   xsbA[2 * CH * FF], xsbB[2 * CH * FF];
    __shared__ __align__(16) float gxbA[2 * CH * NG], gxbB[2 * CH * NG];

    // ---- x chunk staging: lane (sl,wl) covers step sl, quarter wl ----
    const int sl = lane >> 2;
    const int wl = lane & 3;
    const int t0 = dir ? (TT - 1 - sl) : sl;
    const float* xpA = x + (size_t)t0 * (BB * FF) + (size_t)bbA * FF + wl * 4;
    const float* xpB = x + (size_t)t0 * (BB * FF) + (size_t)bbB * FF + wl * 4;
    const ptrdiff_t dstep = (dir ? -(ptrdiff_t)CH : (ptrdiff_t)CH) * (BB * FF);

    // MFMA scatter base: col (lane&15)=step, row (lane>>4)*4+reg=gate
    const int mst = lane & 15;
    const int mq  = (lane >> 4) * 4;
    const int mxr = (mst & 7) << 2;
    const int bsel = (lane & 15) * FF + (lane >> 4) * 8;

    // prologue: stage chunk 0 both seqs, compute gx[0], prefetch chunk 1
    {
        float4 fA = *(const float4*)xpA;
        float4 fB = *(const float4*)xpB;
        *(v4h*)(xsbA + sl * FF + wl * 4) =
            (v4h){(f16)fA.x, (f16)fA.y, (f16)fA.z, (f16)fA.w};
        *(v4h*)(xsbB + sl * FF + wl * 4) =
            (v4h){(f16)fB.x, (f16)fB.y, (f16)fB.z, (f16)fB.w};
    }
    xpA += dstep; xpB += dstep;
    {
        v8h bxA = {(f16)0,(f16)0,(f16)0,(f16)0,(f16)0,(f16)0,(f16)0,(f16)0};
        v8h bxB = bxA;
        if (lane < 32) { bxA = *(const v8h*)(xsbA + bsel);
                         bxB = *(const v8h*)(xsbB + bsel); }
        float* gwA = gxbA + mst * NG;
        float* gwB = gxbB + mst * NG;
#pragma unroll
        for (int T = 0; T < 8; ++T) {
            f32x4 aA = __builtin_amdgcn_mfma_f32_16x16x32_f16(
                awx[T], bxA, (f32x4){0.f, 0.f, 0.f, 0.f}, 0, 0, 0);
            f32x4 aB = __builtin_amdgcn_mfma_f32_16x16x32_f16(
                awx[T], bxB, (f32x4){0.f, 0.f, 0.f, 0.f}, 0, 0, 0);
            *(f32x4*)(gwA + ((mq + T * 16) ^ mxr)) = aA;
            *(f32x4*)(gwB + ((mq + T * 16) ^ mxr)) = aB;
        }
    }
    float4 nfA = *(const float4*)xpA;  xpA += dstep;
    float4 nfB = *(const float4*)xpB;  xpB += dstep;

    float cA = 0.0f, hA = 0.0f, cB = 0.0f, hB = 0.0f;
    int hsA[HH / 2], hsB[HH / 2];     // packed f16 h-pairs (wave-uniform)
#pragma unroll
    for (int m = 0; m < HH / 2; ++m) { hsA[m] = 0; hsB[m] = 0; }

    for (int ci = 0; ci < NC; ++ci) {
        const int bufc = ci & 1;
        const int bufn = bufc ^ 1;
        const bool more = (ci + 1 < NC);

        // chunk top: stage next x into LDS, read bx, issue global prefetch
        v8h bxA = {(f16)0,(f16)0,(f16)0,(f16)0,(f16)0,(f16)0,(f16)0,(f16)0};
        v8h bxB = bxA;
        if (more) {
            *(v4h*)(xsbA + bufn * (CH * FF) + sl * FF + wl * 4) =
                (v4h){(f16)nfA.x, (f16)nfA.y, (f16)nfA.z, (f16)nfA.w};
            *(v4h*)(xsbB + bufn * (CH * FF) + sl * FF + wl * 4) =
                (v4h){(f16)nfB.x, (f16)nfB.y, (f16)nfB.z, (f16)nfB.w};
            if (lane < 32) {
                bxA = *(const v8h*)(xsbA + bufn * (CH * FF) + bsel);
                bxB = *(const v8h*)(xsbB + bufn * (CH * FF) + bsel);
            }
            if (ci + 2 < NC) {
                nfA = *(const float4*)xpA;  xpA += dstep;
                nfB = *(const float4*)xpB;  xpB += dstep;
            }
        }

        const float* gxcA = gxbA + bufc * (CH * NG);
        const float* gxcB = gxbB + bufc * (CH * NG);

#pragma unroll
        for (int tt = 0; tt < 12; ++tt) { LSTEP(tt, A) LSTEP(tt, B) }

        // deferred staging compute for chunk ci+1 (consumed >=4 steps later)
        if (more) {
            float* gwA = gxbA + bufn * (CH * NG) + mst * NG;
            float* gwB = gxbB + bufn * (CH * NG) + mst * NG;
#pragma unroll
            for (int T = 0; T < 8; ++T) {
                f32x4 aA = __builtin_amdgcn_mfma_f32_16x16x32_f16(
                    awx[T], bxA, (f32x4){0.f, 0.f, 0.f, 0.f}, 0, 0, 0);
                f32x4 aB = __builtin_amdgcn_mfma_f32_16x16x32_f16(
                    awx[T], bxB, (f32x4){0.f, 0.f, 0.f, 0.f}, 0, 0, 0);
                *(f32x4*)(gwA + ((mq + T * 16) ^ mxr)) = aA;
                *(f32x4*)(gwB + ((mq + T * 16) ^ mxr)) = aB;
            }
        }

#pragma unroll
        for (int tt = 12; tt < CH; ++tt) { LSTEP(tt, A) LSTEP(tt, B) }
    }

    if (hi) {
        hidden[(size_t)bbA * 64 + dir * HH + kk] = hA;
        hidden[(size_t)bbB * 64 + dir * HH + kk] = hB;
    }
}

// FC1 + per-block partial of FC2. Grid: 32 blocks x 256 threads.
__global__ __launch_bounds__(256)
void fc_partial_kernel(const float* __restrict__ hidden,
                       const float* __restrict__ Wfh, const float* __restrict__ bfh,
                       const float* __restrict__ Wfo,
                       float* __restrict__ partials)
{
    __shared__ float wsh[OO * 64];
    const int tid = threadIdx.x;
    for (int i = tid; i < OO * 64; i += 256) wsh[i] = Wfh[i];
    __syncthreads();

    const int r   = tid >> 3;
    const int o   = tid & 7;
    const int row = blockIdx.x * 32 + r;

    const float* hrow = hidden + (size_t)row * 64;
    float acc = bfh[o];
#pragma unroll
    for (int j = 0; j < 64; ++j) acc += hrow[j] * wsh[o * 64 + j];

    const int fidx = blockIdx.x * 256 + tid;

    float pv[OO];
#pragma unroll
    for (int o2 = 0; o2 < OO; ++o2) pv[o2] = Wfo[(size_t)o2 * (BB * OO) + fidx] * acc;

    __shared__ float red[4][OO];
#pragma unroll
    for (int o2 = 0; o2 < OO; ++o2) {
        float v = pv[o2];
        for (int off = 32; off > 0; off >>= 1) v += __shfl_down(v, off);
        if ((tid & 63) == 0) red[tid >> 6][o2] = v;
    }
    __syncthreads();
    if (tid < OO) {
        partials[blockIdx.x * OO + tid] =
            red[0][tid] + red[1][tid] + red[2][tid] + red[3][tid];
    }
}

__global__ void finalize_kernel(const float* __restrict__ partials,
                                const float* __restrict__ bfo,
                                float* __restrict__ out)
{
    __shared__ float s[OO];
    const int tid = threadIdx.x;
    if (tid < OO) {
        float acc = bfo[tid];
        for (int b = 0; b < 32; ++b) acc += partials[b * OO + tid];
        s[tid] = acc;
    }
    __syncthreads();
    if (tid == 0) {
        float m = s[0];
        for (int i = 1; i < OO; ++i) m = fmaxf(m, s[i]);
        float e[OO], sum = 0.0f;
        for (int i = 0; i < OO; ++i) { e[i] = expf(s[i] - m); sum += e[i]; }
        for (int i = 0; i < OO; ++i) out[i] = e[i] / sum;
    }
}

extern "C" void kernel_launch(void* const* d_in, const int* in_sizes, int n_in,
                              void* d_out, int out_size, void* d_ws, size_t ws_size,
                              hipStream_t stream) {
    const float* x     = (const float*)d_in[0];
    const float* Wih_f = (const float*)d_in[1];
    const float* Whh_f = (const float*)d_in[2];
    const float* b_f   = (const float*)d_in[3];
    const float* Wih_b = (const float*)d_in[4];
    const float* Whh_b = (const float*)d_in[5];
    const float* b_b   = (const float*)d_in[6];
    const float* Wfh   = (const float*)d_in[7];
    const float* bfh   = (const float*)d_in[8];
    const float* Wfo   = (const float*)d_in[9];
    const float* bfo   = (const float*)d_in[10];

    float* hidden   = (float*)d_ws;
    float* partials = hidden + (size_t)BB * 64;

    lstm_seq_kernel<<<BB, 64, 0, stream>>>(x, Wih_f, Whh_f, b_f,
                                           Wih_b, Whh_b, b_b, hidden);
    fc_partial_kernel<<<32, 256, 0, stream>>>(hidden, Wfh, bfh, Wfo, partials);
    finalize_kernel<<<1, 64, 0, stream>>>(partials, bfo, (float*)d_out);
}

// Round 13
// 185.697 us; speedup vs baseline: 1.0227x; 1.0227x over previous
//
#include <hip/hip_runtime.h>

#define TT 512
#define BB 1024
#define FF 16
#define HH 32
#define OO 8
#define CH 16             // timesteps per x-chunk
#define NC (TT / CH)      // 32 chunks
#define NG 128            // gate rows (4*HH)

typedef _Float16 f16;
typedef f16 v2h __attribute__((ext_vector_type(2)));
typedef f16 v4h __attribute__((ext_vector_type(4)));
typedef f16 v8h __attribute__((ext_vector_type(8)));
typedef float f32x4 __attribute__((ext_vector_type(4)));
typedef int   v2i  __attribute__((ext_vector_type(2)));

__device__ __forceinline__ float rcp_fast(float x) { return __builtin_amdgcn_rcpf(x); }
// inputs PRE-SCALED by log2e (resp. 2*log2e) -> plain exp2
__device__ __forceinline__ float sigm2(float y) {
    return rcp_fast(1.0f + __builtin_amdgcn_exp2f(-y));
}
__device__ __forceinline__ float fdot2(v2h a, v2h b, float c) {
    return __builtin_amdgcn_fdot2(a, b, c, false);
}
__device__ __forceinline__ v2h i2h(int s) { return __builtin_bit_cast(v2h, s); }

// cross-half exchange WITHOUT a DS op (gfx950 VALU permlane).
__device__ __forceinline__ float xhalf_swap(float v) {
#if __has_builtin(__builtin_amdgcn_permlane32_swap)
    int pi = __float_as_int(v);
    v2i sw = __builtin_amdgcn_permlane32_swap(pi, pi, false, false);
    return __int_as_float(sw.x);
#else
    return __shfl_xor(v, 32);
#endif
}

// -------- software-pipelined step halves --------
// DOTS: gx reads + 32 dot2 -> carried gS0,gS1   (tt compile-time)
#define DOTS(S, gxp, tt)                                                       \
  {                                                                            \
    const int xm = ((tt) & 7) << 2;                                            \
    const float gx0 = (gxp)[(tt) * NG + (r0 ^ xm)];                            \
    const float gx1 = (gxp)[(tt) * NG + (r1 ^ xm)];                            \
    float B0 = fdot2(i2h(hs##S[0]), w0h[0], pb0);                              \
    float B1 = fdot2(i2h(hs##S[0]), w1h[0], pb1);                              \
    float C0 = fdot2(i2h(hs##S[8]), w0h[8], gx0);                              \
    float C1 = fdot2(i2h(hs##S[8]), w1h[8], gx1);                              \
    _Pragma("unroll")                                                          \
    for (int j = 1; j < 8; ++j) {                                              \
      B0 = fdot2(i2h(hs##S[j]),     w0h[j],     B0);                           \
      B1 = fdot2(i2h(hs##S[j]),     w1h[j],     B1);                           \
      C0 = fdot2(i2h(hs##S[8 + j]), w0h[8 + j], C0);                           \
      C1 = fdot2(i2h(hs##S[8 + j]), w1h[8 + j], C1);                           \
    }                                                                          \
    g##S##0 = B0 + C0;                                                         \
    g##S##1 = B1 + C1;                                                         \
  }

// ACT: activations + c/h update + h re-broadcast (consumes gS0,gS1)
#define ACT(S)                                                                 \
  {                                                                            \
    const float s0 = sigm2(g##S##0);               /* si (lo) / sf (hi) */     \
    const float s1 = fmaf(sigm2(g##S##1), pm, pa); /* tg (lo) / so (hi) */     \
    const float prod = s0 * s1;                                                \
    const float recv = xhalf_swap(prod);                                       \
    c##S = fmaf(s0, c##S, recv);                   /* hi: sf*c + si*tg */      \
    const float th = fmaf(2.0f, sigm2(L2E2 * c##S), -1.0f);                    \
    h##S = s1 * th;                                /* hi: so*tanh(c) */        \
    const int hn = __builtin_amdgcn_mov_dpp(__float_as_int(h##S),              \
                                            0xB1, 0xF, 0xF, true);             \
    auto pk = __builtin_amdgcn_cvt_pkrtz(h##S, __int_as_float(hn));            \
    const int pki = __builtin_bit_cast(int, pk);                               \
    _Pragma("unroll")                                                          \
    for (int m = 0; m < HH / 2; ++m)                                           \
      hs##S[m] = __builtin_amdgcn_readlane(pki, 32 + 2 * m);                   \
  }

// One wave per block, TWO same-direction sequences per wave (1024 blocks,
// 1 wave/SIMD). r12 structure + STAGGERED schedule: the rotation
//   ACT_A(t); DOTS_A(t+1); ACT_B(t); DOTS_B(t+1)
// bridges every chain gap of one sequence with ~300cy of the other's
// independent issue. Carried gA*/gB* hold dot results across the rotation.
// x-part batched per 16-step chunk on the matrix pipe (XOR-swizzled LDS);
// no barriers (single-wave block, DS is in-order per wave).
__global__ __launch_bounds__(64, 1)
void lstm_seq_kernel(const float* __restrict__ x,
                     const float* __restrict__ Wih_f, const float* __restrict__ Whh_f,
                     const float* __restrict__ b_f,
                     const float* __restrict__ Wih_b, const float* __restrict__ Whh_b,
                     const float* __restrict__ b_b,
                     float* __restrict__ hidden)
{
    const int bid  = blockIdx.x;          // 0..1023
    const int dir  = bid >> 9;            // 0 = fwd, 1 = bwd
    const int bbA  = (bid & 511) * 2;     // batch rows (same-dir pair)
    const int bbB  = bbA + 1;
    const int lane = threadIdx.x;
    const int hi   = lane >> 5;           // 0: rows {i,g}   1: rows {f,o}
    const int kk   = lane & 31;

    const float* __restrict__ Wih  = dir ? Wih_b : Wih_f;
    const float* __restrict__ Whh  = dir ? Whh_b : Whh_f;
    const float* __restrict__ bias = dir ? b_b   : b_f;

    const float LOG2E = 1.4426950408889634f;
    const float L2E2  = 2.0f * LOG2E;

    const int r0 = kk + hi * HH;      // i (hi=0) / f (hi=1)
    const int r1 = r0 + 2 * HH;       // g (hi=0) / o (hi=1)
    const float sc0 = LOG2E;
    const float sc1 = hi ? LOG2E : L2E2;
    const float pm = hi ? 1.0f : 2.0f;
    const float pa = hi ? 0.0f : -1.0f;

    // ---- recurrent weights (shared by both seqs): f16 pairs, pre-scaled ----
    v2h w0h[HH / 2], w1h[HH / 2];
#pragma unroll
    for (int q = 0; q < HH / 4; ++q) {
        float4 a = ((const float4*)(Whh + r0 * HH))[q];
        w0h[2*q]   = (v2h){(f16)(a.x * sc0), (f16)(a.y * sc0)};
        w0h[2*q+1] = (v2h){(f16)(a.z * sc0), (f16)(a.w * sc0)};
        float4 b2 = ((const float4*)(Whh + r1 * HH))[q];
        w1h[2*q]   = (v2h){(f16)(b2.x * sc1), (f16)(b2.y * sc1)};
        w1h[2*q+1] = (v2h){(f16)(b2.z * sc1), (f16)(b2.w * sc1)};
    }
    const float pb0 = bias[r0] * sc0;
    const float pb1 = bias[r1] * sc1;

    // ---- MFMA A-fragments for the x-GEMM (shared), k padded 16->32 ----
    v8h awx[8];
#pragma unroll
    for (int T = 0; T < 8; ++T) {
        v8h t = {(f16)0,(f16)0,(f16)0,(f16)0,(f16)0,(f16)0,(f16)0,(f16)0};
        if (lane < 32) {
            const int gate = T * 16 + (lane & 15);
            const float sc = (gate >= 64 && gate < 96) ? L2E2 : LOG2E;
            const float* wrow = Wih + gate * FF + (lane >> 4) * 8;
#pragma unroll
            for (int j = 0; j < 8; ++j) t[j] = (f16)(wrow[j] * sc);
        }
        awx[T] = t;
    }

    __shared__ __align__(16) f16   xsbA[2 * CH * FF], xsbB[2 * CH * FF];
    __shared__ __align__(16) float gxbA[2 * CH * NG], gxbB[2 * CH * NG];

    // ---- x chunk staging: lane (sl,wl) covers step sl, quarter wl ----
    const int sl = lane >> 2;
    const int wl = lane & 3;
    const int t0 = dir ? (TT - 1 - sl) : sl;
    const float* xpA = x + (size_t)t0 * (BB * FF) + (size_t)bbA * FF + wl * 4;
    const float* xpB = x + (size_t)t0 * (BB * FF) + (size_t)bbB * FF + wl * 4;
    const ptrdiff_t dstep = (dir ? -(ptrdiff_t)CH : (ptrdiff_t)CH) * (BB * FF);

    // MFMA scatter base: col (lane&15)=step, row (lane>>4)*4+reg=gate
    const int mst = lane & 15;
    const int mq  = (lane >> 4) * 4;
    const int mxr = (mst & 7) << 2;
    const int bsel = (lane & 15) * FF + (lane >> 4) * 8;

    // prologue: stage chunk 0 both seqs, compute gx[0], prefetch chunk 1
    {
        float4 fA = *(const float4*)xpA;
        float4 fB = *(const float4*)xpB;
        *(v4h*)(xsbA + sl * FF + wl * 4) =
            (v4h){(f16)fA.x, (f16)fA.y, (f16)fA.z, (f16)fA.w};
        *(v4h*)(xsbB + sl * FF + wl * 4) =
            (v4h){(f16)fB.x, (f16)fB.y, (f16)fB.z, (f16)fB.w};
    }
    xpA += dstep; xpB += dstep;
    {
        v8h bxA = {(f16)0,(f16)0,(f16)0,(f16)0,(f16)0,(f16)0,(f16)0,(f16)0};
        v8h bxB = bxA;
        if (lane < 32) { bxA = *(const v8h*)(xsbA + bsel);
                         bxB = *(const v8h*)(xsbB + bsel); }
        float* gwA = gxbA + mst * NG;
        float* gwB = gxbB + mst * NG;
#pragma unroll
        for (int T = 0; T < 8; ++T) {
            f32x4 aA = __builtin_amdgcn_mfma_f32_16x16x32_f16(
                awx[T], bxA, (f32x4){0.f, 0.f, 0.f, 0.f}, 0, 0, 0);
            f32x4 aB = __builtin_amdgcn_mfma_f32_16x16x32_f16(
                awx[T], bxB, (f32x4){0.f, 0.f, 0.f, 0.f}, 0, 0, 0);
            *(f32x4*)(gwA + ((mq + T * 16) ^ mxr)) = aA;
            *(f32x4*)(gwB + ((mq + T * 16) ^ mxr)) = aB;
        }
    }
    float4 nfA = *(const float4*)xpA;  xpA += dstep;
    float4 nfB = *(const float4*)xpB;  xpB += dstep;

    float cA = 0.0f, hA = 0.0f, cB = 0.0f, hB = 0.0f;
    float gA0, gA1, gB0, gB1;         // carried dot results (pipeline regs)
    int hsA[HH / 2], hsB[HH / 2];     // packed f16 h-pairs (wave-uniform)
#pragma unroll
    for (int m = 0; m < HH / 2; ++m) { hsA[m] = 0; hsB[m] = 0; }

    // prime the pipeline: dots for step 0 of both seqs (h = 0)
    DOTS(A, gxbA, 0)
    DOTS(B, gxbB, 0)

    for (int ci = 0; ci < NC; ++ci) {
        const int bufc = ci & 1;
        const int bufn = bufc ^ 1;
        const bool more = (ci + 1 < NC);

        // chunk top: stage next x into LDS, read bx, issue global prefetch
        v8h bxA = {(f16)0,(f16)0,(f16)0,(f16)0,(f16)0,(f16)0,(f16)0,(f16)0};
        v8h bxB = bxA;
        if (more) {
            *(v4h*)(xsbA + bufn * (CH * FF) + sl * FF + wl * 4) =
                (v4h){(f16)nfA.x, (f16)nfA.y, (f16)nfA.z, (f16)nfA.w};
            *(v4h*)(xsbB + bufn * (CH * FF) + sl * FF + wl * 4) =
                (v4h){(f16)nfB.x, (f16)nfB.y, (f16)nfB.z, (f16)nfB.w};
            if (lane < 32) {
                bxA = *(const v8h*)(xsbA + bufn * (CH * FF) + bsel);
                bxB = *(const v8h*)(xsbB + bufn * (CH * FF) + bsel);
            }
            if (ci + 2 < NC) {
                nfA = *(const float4*)xpA;  xpA += dstep;
                nfB = *(const float4*)xpB;  xpB += dstep;
            }
        }

        const float* gxcA = gxbA + bufc * (CH * NG);
        const float* gxcB = gxbB + bufc * (CH * NG);
        const float* gxnA = gxbA + bufn * (CH * NG);
        const float* gxnB = gxbB + bufn * (CH * NG);

#pragma unroll
        for (int tt = 0; tt < CH; ++tt) {
            // staggered rotation: each chain gap is bridged by the other seq
            ACT(A)
            if (tt < CH - 1)      { DOTS(A, gxcA, tt + 1) }
            else if (more)        { DOTS(A, gxnA, 0) }
            ACT(B)
            if (tt < CH - 1)      { DOTS(B, gxcB, tt + 1) }
            else if (more)        { DOTS(B, gxnB, 0) }

            // deferred staging: 8+8 MFMA + gxb writes for chunk ci+1.
            // In DS program order this precedes tt==15's next-chunk DOTS.
            if (tt == 11 && more) {
                float* gwA = gxbA + bufn * (CH * NG) + mst * NG;
                float* gwB = gxbB + bufn * (CH * NG) + mst * NG;
#pragma unroll
                for (int T = 0; T < 8; ++T) {
                    f32x4 aA = __builtin_amdgcn_mfma_f32_16x16x32_f16(
                        awx[T], bxA, (f32x4){0.f, 0.f, 0.f, 0.f}, 0, 0, 0);
                    f32x4 aB = __builtin_amdgcn_mfma_f32_16x16x32_f16(
                        awx[T], bxB, (f32x4){0.f, 0.f, 0.f, 0.f}, 0, 0, 0);
                    *(f32x4*)(gwA + ((mq + T * 16) ^ mxr)) = aA;
                    *(f32x4*)(gwB + ((mq + T * 16) ^ mxr)) = aB;
                }
            }
        }
    }

    if (hi) {
        hidden[(size_t)bbA * 64 + dir * HH + kk] = hA;
        hidden[(size_t)bbB * 64 + dir * HH + kk] = hB;
    }
}

// FC1 + per-block partial of FC2. Grid: 32 blocks x 256 threads.
__global__ __launch_bounds__(256)
void fc_partial_kernel(const float* __restrict__ hidden,
                       const float* __restrict__ Wfh, const float* __restrict__ bfh,
                       const float* __restrict__ Wfo,
                       float* __restrict__ partials)
{
    __shared__ float wsh[OO * 64];
    const int tid = threadIdx.x;
    for (int i = tid; i < OO * 64; i += 256) wsh[i] = Wfh[i];
    __syncthreads();

    const int r   = tid >> 3;
    const int o   = tid & 7;
    const int row = blockIdx.x * 32 + r;

    const float* hrow = hidden + (size_t)row * 64;
    float acc = bfh[o];
#pragma unroll
    for (int j = 0; j < 64; ++j) acc += hrow[j] * wsh[o * 64 + j];

    const int fidx = blockIdx.x * 256 + tid;

    float pv[OO];
#pragma unroll
    for (int o2 = 0; o2 < OO; ++o2) pv[o2] = Wfo[(size_t)o2 * (BB * OO) + fidx] * acc;

    __shared__ float red[4][OO];
#pragma unroll
    for (int o2 = 0; o2 < OO; ++o2) {
        float v = pv[o2];
        for (int off = 32; off > 0; off >>= 1) v += __shfl_down(v, off);
        if ((tid & 63) == 0) red[tid >> 6][o2] = v;
    }
    __syncthreads();
    if (tid < OO) {
        partials[blockIdx.x * OO + tid] =
            red[0][tid] + red[1][tid] + red[2][tid] + red[3][tid];
    }
}

__global__ void finalize_kernel(const float* __restrict__ partials,
                                const float* __restrict__ bfo,
                                float* __restrict__ out)
{
    __shared__ float s[OO];
    const int tid = threadIdx.x;
    if (tid < OO) {
        float acc = bfo[tid];
        for (int b = 0; b < 32; ++b) acc += partials[b * OO + tid];
        s[tid] = acc;
    }
    __syncthreads();
    if (tid == 0) {
        float m = s[0];
        for (int i = 1; i < OO; ++i) m = fmaxf(m, s[i]);
        float e[OO], sum = 0.0f;
        for (int i = 0; i < OO; ++i) { e[i] = expf(s[i] - m); sum += e[i]; }
        for (int i = 0; i < OO; ++i) out[i] = e[i] / sum;
    }
}

extern "C" void kernel_launch(void* const* d_in, const int* in_sizes, int n_in,
                              void* d_out, int out_size, void* d_ws, size_t ws_size,
                              hipStream_t stream) {
    const float* x     = (const float*)d_in[0];
    const float* Wih_f = (const float*)d_in[1];
    const float* Whh_f = (const float*)d_in[2];
    const float* b_f   = (const float*)d_in[3];
    const float* Wih_b = (const float*)d_in[4];
    const float* Whh_b = (const float*)d_in[5];
    const float* b_b   = (const float*)d_in[6];
    const float* Wfh   = (const float*)d_in[7];
    const float* bfh   = (const float*)d_in[8];
    const float* Wfo   = (const float*)d_in[9];
    const float* bfo   = (const float*)d_in[10];

    float* hidden   = (float*)d_ws;
    float* partials = hidden + (size_t)BB * 64;

    lstm_seq_kernel<<<BB, 64, 0, stream>>>(x, Wih_f, Whh_f, b_f,
                                           Wih_b, Whh_b, b_b, hidden);
    fc_partial_kernel<<<32, 256, 0, stream>>>(hidden, Wfh, bfh, Wfo, partials);
    finalize_kernel<<<1, 64, 0, stream>>>(partials, bfo, (float*)d_out);
}

// Round 14
// 175.961 us; speedup vs baseline: 1.0793x; 1.0553x over previous
//
#include <hip/hip_runtime.h>

#define TT 512
#define BB 1024
#define FF 16
#define HH 32
#define OO 8
#define CH 16             // timesteps per x-chunk
#define NC (TT / CH)      // 32 chunks
#define NG 128            // gate rows (4*HH)

typedef _Float16 f16;
typedef f16 v2h __attribute__((ext_vector_type(2)));
typedef f16 v4h __attribute__((ext_vector_type(4)));
typedef f16 v8h __attribute__((ext_vector_type(8)));
typedef float f32x4 __attribute__((ext_vector_type(4)));
typedef int   v2i  __attribute__((ext_vector_type(2)));

__device__ __forceinline__ float rcp_fast(float x) { return __builtin_amdgcn_rcpf(x); }
// inputs PRE-SCALED by log2e (resp. 2*log2e) -> plain exp2
__device__ __forceinline__ float sigm2(float y) {
    return rcp_fast(1.0f + __builtin_amdgcn_exp2f(-y));
}
__device__ __forceinline__ float fdot2(v2h a, v2h b, float c) {
    return __builtin_amdgcn_fdot2(a, b, c, false);
}
__device__ __forceinline__ v2h i2h(int s) { return __builtin_bit_cast(v2h, s); }

// cross-half exchange WITHOUT a DS op (gfx950 VALU permlane).
__device__ __forceinline__ float xhalf_swap(float v) {
#if __has_builtin(__builtin_amdgcn_permlane32_swap)
    int pi = __float_as_int(v);
    v2i sw = __builtin_amdgcn_permlane32_swap(pi, pi, false, false);
    return __int_as_float(sw.x);
#else
    return __shfl_xor(v, 32);
#endif
}

// One LSTM timestep with gx SOFTWARE PREFETCH:
// consumes carried pgx0/pgx1 (loaded one full step earlier, ~330cy slack),
// and issues the loads for the NEXT step (nptr/ntt) at the top.
#define LSTEP(nptr, ntt)                                                       \
  {                                                                            \
    const int nxm = ((ntt) & 7) << 2;                                          \
    const float ngx0 = (nptr)[(ntt) * NG + (r0 ^ nxm)];                        \
    const float ngx1 = (nptr)[(ntt) * NG + (r1 ^ nxm)];                        \
    float B0 = fdot2(i2h(hs[0]), w0h[0], pb0);                                 \
    float B1 = fdot2(i2h(hs[0]), w1h[0], pb1);                                 \
    float C0 = fdot2(i2h(hs[8]), w0h[8], pgx0);                                \
    float C1 = fdot2(i2h(hs[8]), w1h[8], pgx1);                                \
    _Pragma("unroll")                                                          \
    for (int j = 1; j < 8; ++j) {                                              \
      B0 = fdot2(i2h(hs[j]),     w0h[j],     B0);                              \
      B1 = fdot2(i2h(hs[j]),     w1h[j],     B1);                              \
      C0 = fdot2(i2h(hs[8 + j]), w0h[8 + j], C0);                              \
      C1 = fdot2(i2h(hs[8 + j]), w1h[8 + j], C1);                              \
    }                                                                          \
    const float g0 = B0 + C0;                                                  \
    const float g1 = B1 + C1;                                                  \
    const float s0 = sigm2(g0);                /* si (lo) / sf (hi) */         \
    const float s1 = fmaf(sigm2(g1), pm, pa);  /* tg (lo) / so (hi) */         \
    const float prod = s0 * s1;                                                \
    const float recv = xhalf_swap(prod);                                       \
    c = fmaf(s0, c, recv);                     /* hi: sf*c + si*tg */          \
    const float th = fmaf(2.0f, sigm2(L2E2 * c), -1.0f);                       \
    h = s1 * th;                               /* hi: so*tanh(c) */            \
    const int hn = __builtin_amdgcn_mov_dpp(__float_as_int(h),                 \
                                            0xB1, 0xF, 0xF, true);             \
    auto pk = __builtin_amdgcn_cvt_pkrtz(h, __int_as_float(hn));               \
    const int pki = __builtin_bit_cast(int, pk);                               \
    _Pragma("unroll")                                                          \
    for (int m = 0; m < HH / 2; ++m)                                           \
      hs[m] = __builtin_amdgcn_readlane(pki, 32 + 2 * m);                      \
    pgx0 = ngx0; pgx1 = ngx1;                                                  \
  }

// One wave per block, one sequence per wave (2048 blocks, 2 waves/SIMD).
// r11 validated structure (best: 184.6us): row-split full-k dots vs SGPR h,
// x-part batched per 16-step chunk on the matrix pipe into XOR-swizzled
// LDS, deferred staging at tt==11, no barriers (single-wave block, DS
// in-order). NEW: one-step gx register prefetch (pgx0/pgx1) removes the
// ~120cy LDS read latency from the per-step critical chain.
__global__ __launch_bounds__(64, 2)
void lstm_seq_kernel(const float* __restrict__ x,
                     const float* __restrict__ Wih_f, const float* __restrict__ Whh_f,
                     const float* __restrict__ b_f,
                     const float* __restrict__ Wih_b, const float* __restrict__ Whh_b,
                     const float* __restrict__ b_b,
                     float* __restrict__ hidden)
{
    const int bid  = blockIdx.x;          // 0..2047
    const int dir  = bid >> 10;           // 0 = fwd, 1 = bwd
    const int bb   = bid & (BB - 1);      // batch row
    const int lane = threadIdx.x;
    const int hi   = lane >> 5;           // 0: rows {i,g}   1: rows {f,o}
    const int kk   = lane & 31;

    const float* __restrict__ Wih  = dir ? Wih_b : Wih_f;
    const float* __restrict__ Whh  = dir ? Whh_b : Whh_f;
    const float* __restrict__ bias = dir ? b_b   : b_f;

    const float LOG2E = 1.4426950408889634f;
    const float L2E2  = 2.0f * LOG2E;

    const int r0 = kk + hi * HH;      // i (hi=0) / f (hi=1)
    const int r1 = r0 + 2 * HH;       // g (hi=0) / o (hi=1)
    const float sc0 = LOG2E;
    const float sc1 = hi ? LOG2E : L2E2;
    const float pm = hi ? 1.0f : 2.0f;
    const float pa = hi ? 0.0f : -1.0f;

    // ---- recurrent weights: 2 rows x 16 h-pairs, f16, pre-scaled ----
    v2h w0h[HH / 2], w1h[HH / 2];
#pragma unroll
    for (int q = 0; q < HH / 4; ++q) {
        float4 a = ((const float4*)(Whh + r0 * HH))[q];
        w0h[2*q]   = (v2h){(f16)(a.x * sc0), (f16)(a.y * sc0)};
        w0h[2*q+1] = (v2h){(f16)(a.z * sc0), (f16)(a.w * sc0)};
        float4 b2 = ((const float4*)(Whh + r1 * HH))[q];
        w1h[2*q]   = (v2h){(f16)(b2.x * sc1), (f16)(b2.y * sc1)};
        w1h[2*q+1] = (v2h){(f16)(b2.z * sc1), (f16)(b2.w * sc1)};
    }
    const float pb0 = bias[r0] * sc0;
    const float pb1 = bias[r1] * sc1;

    // ---- MFMA A-fragments for the x-GEMM (validated r8/r9) ----
    v8h awx[8];
#pragma unroll
    for (int T = 0; T < 8; ++T) {
        v8h t = {(f16)0,(f16)0,(f16)0,(f16)0,(f16)0,(f16)0,(f16)0,(f16)0};
        if (lane < 32) {
            const int gate = T * 16 + (lane & 15);
            const float sc = (gate >= 64 && gate < 96) ? L2E2 : LOG2E;
            const float* wrow = Wih + gate * FF + (lane >> 4) * 8;
#pragma unroll
            for (int j = 0; j < 8; ++j) t[j] = (f16)(wrow[j] * sc);
        }
        awx[T] = t;
    }

    __shared__ __align__(16) f16   xsb[2 * CH * FF];   // 1 KB: x chunks (f16)
    __shared__ __align__(16) float gxb[2 * CH * NG];   // 16 KB: x-gates (f32)

    // ---- x chunk staging: lane (sl,wl) covers step sl, quarter wl ----
    const int sl = lane >> 2;
    const int wl = lane & 3;
    const int t0 = dir ? (TT - 1 - sl) : sl;
    const float* xp = x + (size_t)t0 * (BB * FF) + (size_t)bb * FF + wl * 4;
    const ptrdiff_t dstep = (dir ? -(ptrdiff_t)CH : (ptrdiff_t)CH) * (BB * FF);

    // MFMA scatter base: col (lane&15)=step, row (lane>>4)*4+reg=gate
    const int mst = lane & 15;
    const int mq  = (lane >> 4) * 4;
    const int mxr = (mst & 7) << 2;

    // prologue: stage chunk 0, compute gx[0], prefetch chunk 1
    {
        float4 f0 = *(const float4*)xp;
        *(v4h*)(xsb + sl * FF + wl * 4) =
            (v4h){(f16)f0.x, (f16)f0.y, (f16)f0.z, (f16)f0.w};
    }
    xp += dstep;
    {
        v8h bx0 = {(f16)0,(f16)0,(f16)0,(f16)0,(f16)0,(f16)0,(f16)0,(f16)0};
        if (lane < 32)
            bx0 = *(const v8h*)(xsb + (lane & 15) * FF + (lane >> 4) * 8);
        float* gw = gxb + mst * NG;
#pragma unroll
        for (int T = 0; T < 8; ++T) {
            f32x4 acc = __builtin_amdgcn_mfma_f32_16x16x32_f16(
                awx[T], bx0, (f32x4){0.f, 0.f, 0.f, 0.f}, 0, 0, 0);
            *(f32x4*)(gw + ((mq + T * 16) ^ mxr)) = acc;
        }
    }
    float4 nf = *(const float4*)xp;   // chunk 1
    xp += dstep;

    float c = 0.0f, h = 0.0f;
    int hs[HH / 2];                   // packed f16 h-pairs (wave-uniform)
#pragma unroll
    for (int m = 0; m < HH / 2; ++m) hs[m] = 0;

    // prime the gx prefetch pipeline: chunk 0, step 0
    float pgx0 = gxb[r0];
    float pgx1 = gxb[r1];

    for (int ci = 0; ci < NC; ++ci) {
        const int bufc = ci & 1;
        const int bufn = bufc ^ 1;
        const bool more = (ci + 1 < NC);

        // chunk top: stage next x into LDS, read bx (long slack), issue
        // the next global prefetch (covered by ~28 steps of compute)
        v8h bx = {(f16)0,(f16)0,(f16)0,(f16)0,(f16)0,(f16)0,(f16)0,(f16)0};
        if (more) {
            *(v4h*)(xsb + bufn * (CH * FF) + sl * FF + wl * 4) =
                (v4h){(f16)nf.x, (f16)nf.y, (f16)nf.z, (f16)nf.w};
            if (lane < 32)
                bx = *(const v8h*)(xsb + bufn * (CH * FF) + (lane & 15) * FF + (lane >> 4) * 8);
            if (ci + 2 < NC) { nf = *(const float4*)xp; xp += dstep; }
        }

        const float* gxc = gxb + bufc * (CH * NG);
        const float* gxn = gxb + bufn * (CH * NG);

        // steps 0..11: prefetch next step from the current chunk
#pragma unroll
        for (int tt = 0; tt < 12; ++tt) LSTEP(gxc, tt + 1)

        // deferred staging compute: 8 MFMA + gxb writes for chunk ci+1.
        // The step-12 prefetch (issued in step 11) precedes these writes in
        // DS program order and reads the CURRENT chunk — safe. The step-0
        // next-chunk prefetch (issued in step 15) follows them — also safe.
        if (more) {
            float* gw = gxb + bufn * (CH * NG) + mst * NG;
#pragma unroll
            for (int T = 0; T < 8; ++T) {
                f32x4 acc = __builtin_amdgcn_mfma_f32_16x16x32_f16(
                    awx[T], bx, (f32x4){0.f, 0.f, 0.f, 0.f}, 0, 0, 0);
                *(f32x4*)(gw + ((mq + T * 16) ^ mxr)) = acc;
            }
        }

        // steps 12..14: still prefetching within the current chunk
#pragma unroll
        for (int tt = 12; tt < CH - 1; ++tt) LSTEP(gxc, tt + 1)

        // step 15: prefetch step 0 of the NEXT chunk (clamped on last)
        if (more) { LSTEP(gxn, 0) }
        else      { LSTEP(gxc, 0) }
    }

    if (hi) hidden[(size_t)bb * 64 + dir * HH + kk] = h;
}

// FC1 + per-block partial of FC2. Grid: 32 blocks x 256 threads.
__global__ __launch_bounds__(256)
void fc_partial_kernel(const float* __restrict__ hidden,
                       const float* __restrict__ Wfh, const float* __restrict__ bfh,
                       const float* __restrict__ Wfo,
                       float* __restrict__ partials)
{
    __shared__ float wsh[OO * 64];
    const int tid = threadIdx.x;
    for (int i = tid; i < OO * 64; i += 256) wsh[i] = Wfh[i];
    __syncthreads();

    const int r   = tid >> 3;
    const int o   = tid & 7;
    const int row = blockIdx.x * 32 + r;

    const float* hrow = hidden + (size_t)row * 64;
    float acc = bfh[o];
#pragma unroll
    for (int j = 0; j < 64; ++j) acc += hrow[j] * wsh[o * 64 + j];

    const int fidx = blockIdx.x * 256 + tid;

    float pv[OO];
#pragma unroll
    for (int o2 = 0; o2 < OO; ++o2) pv[o2] = Wfo[(size_t)o2 * (BB * OO) + fidx] * acc;

    __shared__ float red[4][OO];
#pragma unroll
    for (int o2 = 0; o2 < OO; ++o2) {
        float v = pv[o2];
        for (int off = 32; off > 0; off >>= 1) v += __shfl_down(v, off);
        if ((tid & 63) == 0) red[tid >> 6][o2] = v;
    }
    __syncthreads();
    if (tid < OO) {
        partials[blockIdx.x * OO + tid] =
            red[0][tid] + red[1][tid] + red[2][tid] + red[3][tid];
    }
}

__global__ void finalize_kernel(const float* __restrict__ partials,
                                const float* __restrict__ bfo,
                                float* __restrict__ out)
{
    __shared__ float s[OO];
    const int tid = threadIdx.x;
    if (tid < OO) {
        float acc = bfo[tid];
        for (int b = 0; b < 32; ++b) acc += partials[b * OO + tid];
        s[tid] = acc;
    }
    __syncthreads();
    if (tid == 0) {
        float m = s[0];
        for (int i = 1; i < OO; ++i) m = fmaxf(m, s[i]);
        float e[OO], sum = 0.0f;
        for (int i = 0; i < OO; ++i) { e[i] = expf(s[i] - m); sum += e[i]; }
        for (int i = 0; i < OO; ++i) out[i] = e[i] / sum;
    }
}

extern "C" void kernel_launch(void* const* d_in, const int* in_sizes, int n_in,
                              void* d_out, int out_size, void* d_ws, size_t ws_size,
                              hipStream_t stream) {
    const float* x     = (const float*)d_in[0];
    const float* Wih_f = (const float*)d_in[1];
    const float* Whh_f = (const float*)d_in[2];
    const float* b_f   = (const float*)d_in[3];
    const float* Wih_b = (const float*)d_in[4];
    const float* Whh_b = (const float*)d_in[5];
    const float* b_b   = (const float*)d_in[6];
    const float* Wfh   = (const float*)d_in[7];
    const float* bfh   = (const float*)d_in[8];
    const float* Wfo   = (const float*)d_in[9];
    const float* bfo   = (const float*)d_in[10];

    float* hidden   = (float*)d_ws;
    float* partials = hidden + (size_t)BB * 64;

    lstm_seq_kernel<<<2 * BB, 64, 0, stream>>>(x, Wih_f, Whh_f, b_f,
                                               Wih_b, Whh_b, b_b, hidden);
    fc_partial_kernel<<<32, 256, 0, stream>>>(hidden, Wfh, bfh, Wfo, partials);
    finalize_kernel<<<1, 64, 0, stream>>>(partials, bfo, (float*)d_out);
}

// Round 15
// 173.908 us; speedup vs baseline: 1.0920x; 1.0118x over previous
//
#include <hip/hip_runtime.h>

#define TT 512
#define BB 1024
#define FF 16
#define HH 32
#define OO 8
#define CH 16             // timesteps per x-chunk
#define NC (TT / CH)      // 32 chunks
#define NG 128            // gate rows (4*HH)

typedef _Float16 f16;
typedef f16 v2h __attribute__((ext_vector_type(2)));
typedef f16 v4h __attribute__((ext_vector_type(4)));
typedef f16 v8h __attribute__((ext_vector_type(8)));
typedef float f32x4 __attribute__((ext_vector_type(4)));
typedef int   v2i  __attribute__((ext_vector_type(2)));

__device__ __forceinline__ float rcp_fast(float x) { return __builtin_amdgcn_rcpf(x); }
// inputs PRE-SCALED by log2e (resp. 2*log2e) -> plain exp2
__device__ __forceinline__ float sigm2(float y) {
    return rcp_fast(1.0f + __builtin_amdgcn_exp2f(-y));
}
__device__ __forceinline__ float fdot2(v2h a, v2h b, float c) {
    return __builtin_amdgcn_fdot2(a, b, c, false);
}
__device__ __forceinline__ v2h i2h(int s) { return __builtin_bit_cast(v2h, s); }

// cross-half exchange WITHOUT a DS op (gfx950 VALU permlane).
__device__ __forceinline__ float xhalf_swap(float v) {
#if __has_builtin(__builtin_amdgcn_permlane32_swap)
    int pi = __float_as_int(v);
    v2i sw = __builtin_amdgcn_permlane32_swap(pi, pi, false, false);
    return __int_as_float(sw.x);
#else
    return __shfl_xor(v, 32);
#endif
}

// One LSTM timestep. gx consumed from carried prefetch regs (pgx0/pgx1,
// loaded one full step earlier); next step's loads issued at the top.
// setprio: 1 during the issue-dense dot block, 0 during the serial tail —
// with the half-step wave phase offset, one wave's dots overlap the
// other's serial region and win arbitration there.
// cp carries c' = 2*log2e*c (tanh scale folded into lo-half pm/pa).
#define LSTEP(nptr, ntt)                                                       \
  {                                                                            \
    const int nxm = ((ntt) & 7) << 2;                                          \
    const float ngx0 = (nptr)[(ntt) * NG + (r0 ^ nxm)];                        \
    const float ngx1 = (nptr)[(ntt) * NG + (r1 ^ nxm)];                        \
    __builtin_amdgcn_s_setprio(1);                                             \
    float B0 = fdot2(i2h(hs[0]), w0h[0], pb0);                                 \
    float B1 = fdot2(i2h(hs[0]), w1h[0], pb1);                                 \
    float C0 = fdot2(i2h(hs[8]), w0h[8], pgx0);                                \
    float C1 = fdot2(i2h(hs[8]), w1h[8], pgx1);                                \
    _Pragma("unroll")                                                          \
    for (int j = 1; j < 8; ++j) {                                              \
      B0 = fdot2(i2h(hs[j]),     w0h[j],     B0);                              \
      B1 = fdot2(i2h(hs[j]),     w1h[j],     B1);                              \
      C0 = fdot2(i2h(hs[8 + j]), w0h[8 + j], C0);                              \
      C1 = fdot2(i2h(hs[8 + j]), w1h[8 + j], C1);                              \
    }                                                                          \
    __builtin_amdgcn_s_setprio(0);                                             \
    const float g0 = B0 + C0;                                                  \
    const float g1 = B1 + C1;                                                  \
    const float s0 = sigm2(g0);                /* si (lo) / sf (hi) */         \
    const float s1 = fmaf(sigm2(g1), pm, pa);  /* tg' (lo) / so (hi) */        \
    const float prod = s0 * s1;                                                \
    const float recv = xhalf_swap(prod);                                       \
    cp = fmaf(s0, cp, recv);                   /* hi: 2log2e*(sf*c+si*tg) */   \
    const float th = fmaf(2.0f, sigm2(cp), -1.0f);   /* tanh(c) */             \
    h = s1 * th;                               /* hi: so*tanh(c) */            \
    const int hn = __builtin_amdgcn_mov_dpp(__float_as_int(h),                 \
                                            0xB1, 0xF, 0xF, true);             \
    auto pk = __builtin_amdgcn_cvt_pkrtz(h, __int_as_float(hn));               \
    const int pki = __builtin_bit_cast(int, pk);                               \
    _Pragma("unroll")                                                          \
    for (int m = 0; m < HH / 2; ++m)                                           \
      hs[m] = __builtin_amdgcn_readlane(pki, 32 + 2 * m);                      \
    pgx0 = ngx0; pgx1 = ngx1;                                                  \
  }

// One wave per block, one sequence per wave (2048 blocks, 2 waves/SIMD).
// r14 validated structure + wave anti-phasing: half-step s_sleep offset for
// one wave of each SIMD pair (persists — no barriers anywhere), so the two
// waves' serial regions never systematically coincide.
__global__ __launch_bounds__(64, 2)
void lstm_seq_kernel(const float* __restrict__ x,
                     const float* __restrict__ Wih_f, const float* __restrict__ Whh_f,
                     const float* __restrict__ b_f,
                     const float* __restrict__ Wih_b, const float* __restrict__ Whh_b,
                     const float* __restrict__ b_b,
                     float* __restrict__ hidden)
{
    const int bid  = blockIdx.x;          // 0..2047
    const int dir  = bid >> 10;           // 0 = fwd, 1 = bwd
    const int bb   = bid & (BB - 1);      // batch row
    const int lane = threadIdx.x;
    const int hi   = lane >> 5;           // 0: rows {i,g}   1: rows {f,o}
    const int kk   = lane & 31;

    const float* __restrict__ Wih  = dir ? Wih_b : Wih_f;
    const float* __restrict__ Whh  = dir ? Whh_b : Whh_f;
    const float* __restrict__ bias = dir ? b_b   : b_f;

    const float LOG2E = 1.4426950408889634f;
    const float L2E2  = 2.0f * LOG2E;

    const int r0 = kk + hi * HH;      // i (hi=0) / f (hi=1)
    const int r1 = r0 + 2 * HH;       // g (hi=0) / o (hi=1)
    const float sc0 = LOG2E;
    const float sc1 = hi ? LOG2E : L2E2;
    // lo half: tg' = (2log2e)*tanh(g) = sigm2(g1)*2*L2E2 - L2E2 (c'-folding)
    const float pm = hi ? 1.0f : 2.0f * L2E2;
    const float pa = hi ? 0.0f : -L2E2;

    // ---- recurrent weights: 2 rows x 16 h-pairs, f16, pre-scaled ----
    v2h w0h[HH / 2], w1h[HH / 2];
#pragma unroll
    for (int q = 0; q < HH / 4; ++q) {
        float4 a = ((const float4*)(Whh + r0 * HH))[q];
        w0h[2*q]   = (v2h){(f16)(a.x * sc0), (f16)(a.y * sc0)};
        w0h[2*q+1] = (v2h){(f16)(a.z * sc0), (f16)(a.w * sc0)};
        float4 b2 = ((const float4*)(Whh + r1 * HH))[q];
        w1h[2*q]   = (v2h){(f16)(b2.x * sc1), (f16)(b2.y * sc1)};
        w1h[2*q+1] = (v2h){(f16)(b2.z * sc1), (f16)(b2.w * sc1)};
    }
    const float pb0 = bias[r0] * sc0;
    const float pb1 = bias[r1] * sc1;

    // ---- MFMA A-fragments for the x-GEMM (validated r8/r9) ----
    v8h awx[8];
#pragma unroll
    for (int T = 0; T < 8; ++T) {
        v8h t = {(f16)0,(f16)0,(f16)0,(f16)0,(f16)0,(f16)0,(f16)0,(f16)0};
        if (lane < 32) {
            const int gate = T * 16 + (lane & 15);
            const float sc = (gate >= 64 && gate < 96) ? L2E2 : LOG2E;
            const float* wrow = Wih + gate * FF + (lane >> 4) * 8;
#pragma unroll
            for (int j = 0; j < 8; ++j) t[j] = (f16)(wrow[j] * sc);
        }
        awx[T] = t;
    }

    __shared__ __align__(16) f16   xsb[2 * CH * FF];   // 1 KB: x chunks (f16)
    __shared__ __align__(16) float gxb[2 * CH * NG];   // 16 KB: x-gates (f32)

    // ---- x chunk staging: lane (sl,wl) covers step sl, quarter wl ----
    const int sl = lane >> 2;
    const int wl = lane & 3;
    const int t0 = dir ? (TT - 1 - sl) : sl;
    const float* xp = x + (size_t)t0 * (BB * FF) + (size_t)bb * FF + wl * 4;
    const ptrdiff_t dstep = (dir ? -(ptrdiff_t)CH : (ptrdiff_t)CH) * (BB * FF);

    // MFMA scatter base: col (lane&15)=step, row (lane>>4)*4+reg=gate
    const int mst = lane & 15;
    const int mq  = (lane >> 4) * 4;
    const int mxr = (mst & 7) << 2;

    // prologue: stage chunk 0, compute gx[0], prefetch chunk 1
    {
        float4 f0 = *(const float4*)xp;
        *(v4h*)(xsb + sl * FF + wl * 4) =
            (v4h){(f16)f0.x, (f16)f0.y, (f16)f0.z, (f16)f0.w};
    }
    xp += dstep;
    {
        v8h bx0 = {(f16)0,(f16)0,(f16)0,(f16)0,(f16)0,(f16)0,(f16)0,(f16)0};
        if (lane < 32)
            bx0 = *(const v8h*)(xsb + (lane & 15) * FF + (lane >> 4) * 8);
        float* gw = gxb + mst * NG;
#pragma unroll
        for (int T = 0; T < 8; ++T) {
            f32x4 acc = __builtin_amdgcn_mfma_f32_16x16x32_f16(
                awx[T], bx0, (f32x4){0.f, 0.f, 0.f, 0.f}, 0, 0, 0);
            *(f32x4*)(gw + ((mq + T * 16) ^ mxr)) = acc;
        }
    }
    float4 nf = *(const float4*)xp;   // chunk 1
    xp += dstep;

    float cp = 0.0f, h = 0.0f;        // cp = 2*log2e * c
    int hs[HH / 2];                   // packed f16 h-pairs (wave-uniform)
#pragma unroll
    for (int m = 0; m < HH / 2; ++m) hs[m] = 0;

    // prime the gx prefetch pipeline: chunk 0, step 0
    float pgx0 = gxb[r0];
    float pgx1 = gxb[r1];

    // ---- wave anti-phasing: offset one wave of each SIMD pair by ~half a
    // step (no barriers anywhere -> the offset persists for all 512 steps).
    // Selector covers both plausible co-residency pairings:
    // (2i,2i+1) differs in bit0; (i,i+1024) differs in bit10.
    if ((bid ^ (bid >> 10)) & 1) __builtin_amdgcn_s_sleep(7);   // ~448 cyc

    for (int ci = 0; ci < NC; ++ci) {
        const int bufc = ci & 1;
        const int bufn = bufc ^ 1;
        const bool more = (ci + 1 < NC);

        // chunk top: stage next x into LDS, read bx (long slack), issue
        // the next global prefetch (covered by ~28 steps of compute)
        v8h bx = {(f16)0,(f16)0,(f16)0,(f16)0,(f16)0,(f16)0,(f16)0,(f16)0};
        if (more) {
            *(v4h*)(xsb + bufn * (CH * FF) + sl * FF + wl * 4) =
                (v4h){(f16)nf.x, (f16)nf.y, (f16)nf.z, (f16)nf.w};
            if (lane < 32)
                bx = *(const v8h*)(xsb + bufn * (CH * FF) + (lane & 15) * FF + (lane >> 4) * 8);
            if (ci + 2 < NC) { nf = *(const float4*)xp; xp += dstep; }
        }

        const float* gxc = gxb + bufc * (CH * NG);
        const float* gxn = gxb + bufn * (CH * NG);

        // steps 0..11: prefetch next step from the current chunk
#pragma unroll
        for (int tt = 0; tt < 12; ++tt) LSTEP(gxc, tt + 1)

        // deferred staging compute: 8 MFMA + gxb writes for chunk ci+1.
        // Step-12 prefetch (issued in step 11) precedes these writes in DS
        // program order and reads the CURRENT chunk — safe. The step-0
        // next-chunk prefetch (issued in step 15) follows them — safe.
        if (more) {
            float* gw = gxb + bufn * (CH * NG) + mst * NG;
#pragma unroll
            for (int T = 0; T < 8; ++T) {
                f32x4 acc = __builtin_amdgcn_mfma_f32_16x16x32_f16(
                    awx[T], bx, (f32x4){0.f, 0.f, 0.f, 0.f}, 0, 0, 0);
                *(f32x4*)(gw + ((mq + T * 16) ^ mxr)) = acc;
            }
        }

        // steps 12..14: still prefetching within the current chunk
#pragma unroll
        for (int tt = 12; tt < CH - 1; ++tt) LSTEP(gxc, tt + 1)

        // step 15: prefetch step 0 of the NEXT chunk (clamped on last)
        if (more) { LSTEP(gxn, 0) }
        else      { LSTEP(gxc, 0) }
    }

    if (hi) hidden[(size_t)bb * 64 + dir * HH + kk] = h;
}

// FC1 + per-block partial of FC2. Grid: 32 blocks x 256 threads.
__global__ __launch_bounds__(256)
void fc_partial_kernel(const float* __restrict__ hidden,
                       const float* __restrict__ Wfh, const float* __restrict__ bfh,
                       const float* __restrict__ Wfo,
                       float* __restrict__ partials)
{
    __shared__ float wsh[OO * 64];
    const int tid = threadIdx.x;
    for (int i = tid; i < OO * 64; i += 256) wsh[i] = Wfh[i];
    __syncthreads();

    const int r   = tid >> 3;
    const int o   = tid & 7;
    const int row = blockIdx.x * 32 + r;

    const float* hrow = hidden + (size_t)row * 64;
    float acc = bfh[o];
#pragma unroll
    for (int j = 0; j < 64; ++j) acc += hrow[j] * wsh[o * 64 + j];

    const int fidx = blockIdx.x * 256 + tid;

    float pv[OO];
#pragma unroll
    for (int o2 = 0; o2 < OO; ++o2) pv[o2] = Wfo[(size_t)o2 * (BB * OO) + fidx] * acc;

    __shared__ float red[4][OO];
#pragma unroll
    for (int o2 = 0; o2 < OO; ++o2) {
        float v = pv[o2];
        for (int off = 32; off > 0; off >>= 1) v += __shfl_down(v, off);
        if ((tid & 63) == 0) red[tid >> 6][o2] = v;
    }
    __syncthreads();
    if (tid < OO) {
        partials[blockIdx.x * OO + tid] =
            red[0][tid] + red[1][tid] + red[2][tid] + red[3][tid];
    }
}

__global__ void finalize_kernel(const float* __restrict__ partials,
                                const float* __restrict__ bfo,
                                float* __restrict__ out)
{
    __shared__ float s[OO];
    const int tid = threadIdx.x;
    if (tid < OO) {
        float acc = bfo[tid];
        for (int b = 0; b < 32; ++b) acc += partials[b * OO + tid];
        s[tid] = acc;
    }
    __syncthreads();
    if (tid == 0) {
        float m = s[0];
        for (int i = 1; i < OO; ++i) m = fmaxf(m, s[i]);
        float e[OO], sum = 0.0f;
        for (int i = 0; i < OO; ++i) { e[i] = expf(s[i] - m); sum += e[i]; }
        for (int i = 0; i < OO; ++i) out[i] = e[i] / sum;
    }
}

extern "C" void kernel_launch(void* const* d_in, const int* in_sizes, int n_in,
                              void* d_out, int out_size, void* d_ws, size_t ws_size,
                              hipStream_t stream) {
    const float* x     = (const float*)d_in[0];
    const float* Wih_f = (const float*)d_in[1];
    const float* Whh_f = (const float*)d_in[2];
    const float* b_f   = (const float*)d_in[3];
    const float* Wih_b = (const float*)d_in[4];
    const float* Whh_b = (const float*)d_in[5];
    const float* b_b   = (const float*)d_in[6];
    const float* Wfh   = (const float*)d_in[7];
    const float* bfh   = (const float*)d_in[8];
    const float* Wfo   = (const float*)d_in[9];
    const float* bfo   = (const float*)d_in[10];

    float* hidden   = (float*)d_ws;
    float* partials = hidden + (size_t)BB * 64;

    lstm_seq_kernel<<<2 * BB, 64, 0, stream>>>(x, Wih_f, Whh_f, b_f,
                                               Wih_b, Whh_b, b_b, hidden);
    fc_partial_kernel<<<32, 256, 0, stream>>>(hidden, Wfh, bfh, Wfo, partials);
    finalize_kernel<<<1, 64, 0, stream>>>(partials, bfo, (float*)d_out);
}